// Round 2
// baseline (229.696 us; speedup 1.0000x reference)
//
#include <hip/hip_runtime.h>
#include <math.h>

// Problem constants (from reference): B=32, I=2048, O=32, C=16, U=32
#define B_   32
#define I_   2048
#define O_   32
#define C_   16
#define U_   32
#define NCOL (O_ * U_)        // 1024 output columns (o,u)

// R5 occupancy probe: 256-thread blocks, TI=4, 4-way o-split -> 2048 blocks
// (8 blocks/CU, 8 waves/SIMD at <=64 VGPR) vs R4's 4 waves/SIMD. Tests the
// latency-bound hypothesis: R3->R4 traffic changes (ws halved, L1 dup x2)
// moved dur <1% -> either partial is HBM-bound (~22us, done) or latency-bound
// at low occupancy (this fixes it).
#define TI   4                // i-values per block
#define OQ_  4                // o-split factor
#define OB_  (O_ / OQ_)       // 8 o-values per block
#define NIH  (I_ / TI)        // 512 i-chunks
#define NBLK (NIH * OQ_)      // 2048 blocks
#define SLICE (B_ * OB_ * U_) // 8192 floats per partial slice (32 KB)
#define XS   36               // x LDS stride: mult-of-4 (b128 align), pad

// softmax over the singleton axis of b_log is identically 1 -> routing
// iterations are no-ops. Output = squash(sum_{i,c} x[b,i,c] * w[i,o,c,u]).

__global__ __launch_bounds__(256, 8) void caps_partial(const float* __restrict__ x,
                                                       const float* __restrict__ w,
                                                       float* __restrict__ ws) {
    __shared__ float xs[TI * C_ * XS];   // xs[rem*36 + b], rem = il*C + c (64 rems)
    const int tid = threadIdx.x;         // 0..255
    const int ih  = blockIdx.x & (NIH - 1);   // i-chunk (0..511)
    const int oq  = blockIdx.x >> 9;          // o-quad (0..3)
    const int i0  = ih * TI;
    const int o0  = oq * OB_;

    // Stage x[:, i0:i0+TI, :] -> xs[rem*XS + b]. Global read coalesced (rem
    // fast). 8 writes/thread, once.
    for (int k = tid; k < B_ * TI * C_; k += 256) {
        int b   = k >> 6;        // / (TI*C_) == 64
        int rem = k & 63;
        xs[rem * XS + b] = x[(size_t)b * (I_ * C_) + (size_t)i0 * C_ + rem];
    }
    __syncthreads();

    // wave = one batch-octet (bh = tid>>6): all LDS x reads are wave-uniform
    // broadcasts (conflict-free). ct covers 8 o x 8 u-quads.
    const int bh = tid >> 6;             // 0..3
    const int ct = tid & 63;
    const int oo = ct >> 3;              // 0..7
    const int u4 = (ct & 7) << 2;
    const float* wp = w + (size_t)i0 * (O_ * C_ * U_) + (size_t)(o0 + oo) * (C_ * U_) + u4;

    float4 acc[8];                       // acc[bl] : b = bh*8+bl, u = u4..u4+3
#pragma unroll
    for (int b = 0; b < 8; ++b) acc[b] = make_float4(0.f, 0.f, 0.f, 0.f);

    for (int il = 0; il < TI; ++il) {
        const float* wpi = wp + (size_t)il * (O_ * C_ * U_);
        const float* xr  = &xs[(il * C_) * XS + bh * 8];
#pragma unroll
        for (int c = 0; c < C_; ++c) {
            float4 wv = *(const float4*)(wpi + c * U_);   // 8 lanes x 16B = 128B segs
            const float4* xv = (const float4*)(xr + c * XS);
            float4 xa = xv[0];           // b = bh*8 + 0..3 (LDS broadcast)
            float4 xb = xv[1];           // b = bh*8 + 4..7 (LDS broadcast)
            acc[0].x = fmaf(xa.x, wv.x, acc[0].x);
            acc[0].y = fmaf(xa.x, wv.y, acc[0].y);
            acc[0].z = fmaf(xa.x, wv.z, acc[0].z);
            acc[0].w = fmaf(xa.x, wv.w, acc[0].w);
            acc[1].x = fmaf(xa.y, wv.x, acc[1].x);
            acc[1].y = fmaf(xa.y, wv.y, acc[1].y);
            acc[1].z = fmaf(xa.y, wv.z, acc[1].z);
            acc[1].w = fmaf(xa.y, wv.w, acc[1].w);
            acc[2].x = fmaf(xa.z, wv.x, acc[2].x);
            acc[2].y = fmaf(xa.z, wv.y, acc[2].y);
            acc[2].z = fmaf(xa.z, wv.z, acc[2].z);
            acc[2].w = fmaf(xa.z, wv.w, acc[2].w);
            acc[3].x = fmaf(xa.w, wv.x, acc[3].x);
            acc[3].y = fmaf(xa.w, wv.y, acc[3].y);
            acc[3].z = fmaf(xa.w, wv.z, acc[3].z);
            acc[3].w = fmaf(xa.w, wv.w, acc[3].w);
            acc[4].x = fmaf(xb.x, wv.x, acc[4].x);
            acc[4].y = fmaf(xb.x, wv.y, acc[4].y);
            acc[4].z = fmaf(xb.x, wv.z, acc[4].z);
            acc[4].w = fmaf(xb.x, wv.w, acc[4].w);
            acc[5].x = fmaf(xb.y, wv.x, acc[5].x);
            acc[5].y = fmaf(xb.y, wv.y, acc[5].y);
            acc[5].z = fmaf(xb.y, wv.z, acc[5].z);
            acc[5].w = fmaf(xb.y, wv.w, acc[5].w);
            acc[6].x = fmaf(xb.z, wv.x, acc[6].x);
            acc[6].y = fmaf(xb.z, wv.y, acc[6].y);
            acc[6].z = fmaf(xb.z, wv.z, acc[6].z);
            acc[6].w = fmaf(xb.z, wv.w, acc[6].w);
            acc[7].x = fmaf(xb.w, wv.x, acc[7].x);
            acc[7].y = fmaf(xb.w, wv.y, acc[7].y);
            acc[7].z = fmaf(xb.w, wv.z, acc[7].z);
            acc[7].w = fmaf(xb.w, wv.w, acc[7].w);
        }
    }

    // ws[blk][b][oo][u], slice = blockIdx (oq*512+ih). Coalesced float4 stores.
    float* op = ws + (size_t)blockIdx.x * SLICE + (size_t)(bh * 8) * (OB_ * U_)
                + oo * U_ + u4;
#pragma unroll
    for (int bl = 0; bl < 8; ++bl)
        *(float4*)(op + (size_t)bl * (OB_ * U_)) = acc[bl];
}

// Sum 512 i-chunk partials per element (2 threads/element over halves),
// then squash over u (32 consecutive e = one (b,o) group; shuffle reduce).
__global__ __launch_bounds__(256) void caps_reduce_squash(const float* __restrict__ ws,
                                                          float* __restrict__ out) {
    __shared__ float sh[128];
    const int tl = threadIdx.x & 127;
    const int ph = threadIdx.x >> 7;           // i-chunk half
    const int e  = blockIdx.x * 128 + tl;      // e in [0, 32768)
    const int b  = e >> 10;
    const int o  = (e >> 5) & 31;
    const int u  = e & 31;
    const int oq = o >> 3;
    const int oo = o & 7;
    const float* p = ws + ((size_t)oq * NIH + (size_t)ph * (NIH / 2)) * SLICE
                     + (size_t)b * (OB_ * U_) + oo * U_ + u;
    float s = 0.f;
#pragma unroll 16
    for (int i = 0; i < NIH / 2; ++i)
        s += p[(size_t)i * SLICE];
    if (ph) sh[tl] = s;
    __syncthreads();
    if (ph == 0) {
        s += sh[tl];
        float ss = s * s;
        ss += __shfl_xor(ss, 1);
        ss += __shfl_xor(ss, 2);
        ss += __shfl_xor(ss, 4);
        ss += __shfl_xor(ss, 8);
        ss += __shfl_xor(ss, 16);
        float n = sqrtf(ss);
        out[e] = s * n / (1.0f + ss);
    }
}

// ---------------- fallback (atomic path) if ws too small ----------------
#define FTI 4
__global__ __launch_bounds__(256, 2) void caps_main_atomic(const float* __restrict__ x,
                                                           const float* __restrict__ w,
                                                           float* __restrict__ out) {
    __shared__ float xs[FTI * C_ * 33];
    const int tid = threadIdx.x;
    const int i0 = blockIdx.x * FTI;
    for (int k = tid; k < B_ * FTI * C_; k += 256) {
        int b = k >> 6, rem = k & 63;
        xs[rem * 33 + b] = x[(size_t)b * (I_ * C_) + (size_t)i0 * C_ + rem];
    }
    __syncthreads();
    const int o = tid >> 3, u4 = (tid & 7) << 2;
    const float* wp = w + (size_t)i0 * (O_ * C_ * U_) + o * (C_ * U_) + u4;
    float4 acc[B_];
#pragma unroll
    for (int b = 0; b < B_; ++b) acc[b] = make_float4(0.f, 0.f, 0.f, 0.f);
    for (int il = 0; il < FTI; ++il) {
        const float* wpi = wp + (size_t)il * (O_ * C_ * U_);
        const float* xr = &xs[il * C_ * 33];
#pragma unroll
        for (int c = 0; c < C_; ++c) {
            float4 wv = *(const float4*)(wpi + c * U_);
            const float* xc = xr + c * 33;
#pragma unroll
            for (int b = 0; b < B_; ++b) {
                float xb = xc[b];
                acc[b].x = fmaf(xb, wv.x, acc[b].x);
                acc[b].y = fmaf(xb, wv.y, acc[b].y);
                acc[b].z = fmaf(xb, wv.z, acc[b].z);
                acc[b].w = fmaf(xb, wv.w, acc[b].w);
            }
        }
    }
    float* op = out + o * U_ + u4;
#pragma unroll
    for (int b = 0; b < B_; ++b) {
        float* p = op + (size_t)b * NCOL;
        atomicAdd(p + 0, acc[b].x);
        atomicAdd(p + 1, acc[b].y);
        atomicAdd(p + 2, acc[b].z);
        atomicAdd(p + 3, acc[b].w);
    }
}

__global__ void caps_squash_inplace(float* __restrict__ out) {
    int t = blockIdx.x * 256 + threadIdx.x;
    float s = out[t];
    float ss = s * s;
    ss += __shfl_xor(ss, 1);
    ss += __shfl_xor(ss, 2);
    ss += __shfl_xor(ss, 4);
    ss += __shfl_xor(ss, 8);
    ss += __shfl_xor(ss, 16);
    float n = sqrtf(ss);
    out[t] = s * n / (1.0f + ss);
}

extern "C" void kernel_launch(void* const* d_in, const int* in_sizes, int n_in,
                              void* d_out, int out_size, void* d_ws, size_t ws_size,
                              hipStream_t stream) {
    const float* x = (const float*)d_in[0];   // [B, I, C]
    const float* w = (const float*)d_in[1];   // [I, O, C, U]
    float* out = (float*)d_out;               // [B, O, 1, U] = 32768 floats

    const size_t need = (size_t)NBLK * SLICE * sizeof(float);   // 64 MB
    if (ws_size >= need) {
        float* ws = (float*)d_ws;
        caps_partial<<<NBLK, 256, 0, stream>>>(x, w, ws);
        caps_reduce_squash<<<(B_ * NCOL) / 128, 256, 0, stream>>>(ws, out);
    } else {
        hipMemsetAsync(out, 0, (size_t)(B_ * NCOL) * sizeof(float), stream);
        caps_main_atomic<<<I_ / FTI, 256, 0, stream>>>(x, w, out);
        caps_squash_inplace<<<(B_ * NCOL) / 256, 256, 0, stream>>>(out);
    }
}